// Round 3
// baseline (1051.056 us; speedup 1.0000x reference)
//
#include <hip/hip_runtime.h>

#define TPB 256
#define NB 391            // ceil(100000/256) coarse buckets of 256 nodes
#define CH 8192           // edges per k_placeA block

// ---------------- coarse histogram (LDS-privatized) ----------------

__global__ __launch_bounds__(TPB) void k_hist(const int* __restrict__ dst,
                                              unsigned* __restrict__ gcount, int E) {
    __shared__ unsigned c[512];
    int t = threadIdx.x;
    for (int b = t; b < 512; b += TPB) c[b] = 0;
    __syncthreads();
    int stride = gridDim.x * TPB;
    for (int i = blockIdx.x * TPB + t; i < E; i += stride)
        atomicAdd(&c[(unsigned)dst[i] >> 8], 1u);
    __syncthreads();
    for (int b = t; b < NB; b += TPB)
        if (c[b]) atomicAdd(&gcount[b], c[b]);
}

// ---------------- exclusive scan over NB buckets (1 block) ----------------

__global__ __launch_bounds__(512) void k_scan(const unsigned* __restrict__ gcount,
                                              int* __restrict__ cptr,
                                              unsigned* __restrict__ gcur, int E) {
    __shared__ unsigned s[512];
    int t = threadIdx.x;
    unsigned orig = (t < NB) ? gcount[t] : 0u;
    s[t] = orig;
    __syncthreads();
#pragma unroll
    for (int o = 1; o < 512; o <<= 1) {
        unsigned v = (t >= o) ? s[t - o] : 0u;
        __syncthreads();
        s[t] += v;
        __syncthreads();
    }
    if (t < NB) {
        unsigned ex = s[t] - orig;
        cptr[t] = (int)ex;
        gcur[t] = ex;
    }
    if (t == 0) cptr[NB] = E;
}

// ---------------- chunked coarse bucket sort, LDS-staged grouped writes ----
// packs each edge as  src | ((dst & 255) << 20)

__global__ __launch_bounds__(TPB) void k_placeA(const int* __restrict__ src,
                                                const int* __restrict__ dst,
                                                unsigned* __restrict__ gcur,
                                                unsigned* __restrict__ bkt, int E) {
    __shared__ unsigned val[CH];
    __shared__ unsigned short bid[CH];
    __shared__ unsigned cnt[512], loff[512], lcur[512], basev[512];
    __shared__ unsigned tsum[TPB];
    int t = threadIdx.x;
    int c0 = blockIdx.x * CH;
    int n = E - c0; if (n > CH) n = CH;

    for (int b = t; b < 512; b += TPB) { cnt[b] = 0; lcur[b] = 0; }
    __syncthreads();
    for (int i = t; i < n; i += TPB)
        atomicAdd(&cnt[(unsigned)dst[c0 + i] >> 8], 1u);
    __syncthreads();
    // reserve contiguous global ranges (one atomic per non-empty bucket)
    for (int b = t; b < NB; b += TPB)
        basev[b] = cnt[b] ? atomicAdd(&gcur[b], cnt[b]) : 0u;
    // exclusive scan of cnt (512 entries, 2 per thread)
    unsigned a0 = cnt[2 * t], a1 = cnt[2 * t + 1];
    tsum[t] = a0 + a1;
    __syncthreads();
#pragma unroll
    for (int o = 1; o < TPB; o <<= 1) {
        unsigned v = (t >= o) ? tsum[t - o] : 0u;
        __syncthreads();
        tsum[t] += v;
        __syncthreads();
    }
    unsigned ex = tsum[t] - (a0 + a1);
    loff[2 * t] = ex; loff[2 * t + 1] = ex + a0;
    __syncthreads();
    // local grouped staging
    for (int i = t; i < n; i += TPB) {
        unsigned s = (unsigned)src[c0 + i];
        unsigned d = (unsigned)dst[c0 + i];
        unsigned b = d >> 8;
        unsigned r = atomicAdd(&lcur[b], 1u);
        unsigned slot = loff[b] + r;
        val[slot] = s | ((d & 255u) << 20);
        bid[slot] = (unsigned short)b;
    }
    __syncthreads();
    // grouped global writes (runs of ~CH/NB consecutive words per bucket)
    for (int i = t; i < n; i += TPB) {
        unsigned b = bid[i];
        bkt[basev[b] + ((unsigned)i - loff[b])] = val[i];
    }
}

// ---------------- per-bucket degree -> dinv ----------------

__global__ __launch_bounds__(TPB) void k_dinvB(const unsigned* __restrict__ bkt,
                                               const int* __restrict__ cptr,
                                               float* __restrict__ dinv, int N) {
    __shared__ unsigned cnt[256];
    int t = threadIdx.x, b = blockIdx.x;
    cnt[t] = 0;
    __syncthreads();
    int p0 = cptr[b], p1 = cptr[b + 1];
    for (int i = p0 + t; i < p1; i += TPB)
        atomicAdd(&cnt[bkt[i] >> 20], 1u);
    __syncthreads();
    int node = (b << 8) + t;
    if (node < N) dinv[node] = rsqrtf((float)(cnt[t] + 1u));
}

// ---------------- xs4 = dinv * x (padded to float4) ----------------

__global__ __launch_bounds__(TPB) void k_scale3(const float* __restrict__ x,
                                                const float* __restrict__ dinv,
                                                float* __restrict__ xs4, int N) {
    int tid = blockIdx.x * TPB + threadIdx.x;
    if (tid >= N * 4) return;
    int node = tid >> 2, c = tid & 3;
    xs4[tid] = (c < 3) ? x[node * 3 + c] * dinv[node] : 0.f;
}

// ---------------- 3-wide (padded-4) LDS aggregation ----------------
// q4[i] = dinv[i] * (xs4[i] + sum_{e:dst=i} xs4[src])

__global__ __launch_bounds__(TPB) void k_agg3(const unsigned* __restrict__ bkt,
                                              const int* __restrict__ cptr,
                                              const float* __restrict__ xs4,
                                              const float* __restrict__ dinv,
                                              float* __restrict__ q4, int N) {
    __shared__ float acc[256 * 4];
    int t = threadIdx.x, b = blockIdx.x;
    for (int i = t; i < 1024; i += TPB) acc[i] = 0.f;
    __syncthreads();
    int p0 = cptr[b], p1 = cptr[b + 1];
    int w = t >> 6, lane = t & 63, q = lane >> 2, c = lane & 3;
    for (int base = p0 + (w << 5); base < p1; base += 128) {  // 2x16 edges/wave/iter
        int e1 = base + q, e2 = base + 16 + q;
        unsigned u1 = (e1 < p1) ? bkt[e1] : 0u;
        unsigned u2 = (e2 < p1) ? bkt[e2] : 0u;
        if (e1 < p1) atomicAdd(&acc[((u1 >> 20) << 2) + c], xs4[((size_t)(u1 & 0xFFFFFu) << 2) + c]);
        if (e2 < p1) atomicAdd(&acc[((u2 >> 20) << 2) + c], xs4[((size_t)(u2 & 0xFFFFFu) << 2) + c]);
    }
    __syncthreads();
    int n0 = b << 8;
    for (int i = t; i < 1024; i += TPB) {
        int node = n0 + (i >> 2);
        if (node >= N) break;
        int cc = i & 3;
        q4[((size_t)node << 2) + cc] = dinv[node] * (xs4[((size_t)node << 2) + cc] + acc[i]);
    }
}

// same, layer-3 epilogue: out[node*3+c] = dinv*(g34self+acc) + b3[c]

__global__ __launch_bounds__(TPB) void k_agg3o(const unsigned* __restrict__ bkt,
                                               const int* __restrict__ cptr,
                                               const float* __restrict__ g34,
                                               const float* __restrict__ dinv,
                                               const float* __restrict__ b3,
                                               float* __restrict__ out, int N) {
    __shared__ float acc[256 * 4];
    int t = threadIdx.x, b = blockIdx.x;
    for (int i = t; i < 1024; i += TPB) acc[i] = 0.f;
    __syncthreads();
    int p0 = cptr[b], p1 = cptr[b + 1];
    int w = t >> 6, lane = t & 63, q = lane >> 2, c = lane & 3;
    for (int base = p0 + (w << 5); base < p1; base += 128) {
        int e1 = base + q, e2 = base + 16 + q;
        unsigned u1 = (e1 < p1) ? bkt[e1] : 0u;
        unsigned u2 = (e2 < p1) ? bkt[e2] : 0u;
        if (e1 < p1) atomicAdd(&acc[((u1 >> 20) << 2) + c], g34[((size_t)(u1 & 0xFFFFFu) << 2) + c]);
        if (e2 < p1) atomicAdd(&acc[((u2 >> 20) << 2) + c], g34[((size_t)(u2 & 0xFFFFFu) << 2) + c]);
    }
    __syncthreads();
    int n0 = b << 8;
    for (int i = t; i < 1024; i += TPB) {
        int node = n0 + (i >> 2);
        if (node >= N) break;
        int cc = i & 3;
        if (cc < 3)
            out[(size_t)node * 3 + cc] =
                dinv[node] * (g34[((size_t)node << 2) + cc] + acc[i]) + b3[cc];
    }
}

// ---------------- 64-wide LDS aggregation (layer 2) ----------------
// h2[n,f] = relu( dinv[n]*(g[n,f] + sum_{e:dst=n} g[src,f]) + b2[f] )

__global__ __launch_bounds__(TPB) void k_agg64(const unsigned* __restrict__ bkt,
                                               const int* __restrict__ cptr,
                                               const float* __restrict__ g,
                                               const float* __restrict__ dinv,
                                               const float* __restrict__ bias,
                                               float* __restrict__ out, int N) {
    __shared__ float acc[256 * 64];          // 64 KB, exactly the static limit
    int t = threadIdx.x, b = blockIdx.x;
    for (int i = t; i < 16384; i += TPB) acc[i] = 0.f;
    __syncthreads();
    int p0 = cptr[b], p1 = cptr[b + 1];
    int wu = __builtin_amdgcn_readfirstlane(t >> 6);   // wave-uniform -> scalar loads of bkt
    int f = t & 63;
    for (int base = p0 + (wu << 6); base < p1; base += 256) {
        int m = p1 - base; if (m > 64) m = 64;
        if (m == 64) {
#pragma unroll 16
            for (int j = 0; j < 64; ++j) {
                unsigned u = bkt[base + j];             // uniform address -> s_load
                int s  = u & 0xFFFFF;
                int dl = u >> 20;
                atomicAdd(&acc[(dl << 6) + f], g[((size_t)s << 6) + f]);
            }
        } else {
            for (int j = 0; j < m; ++j) {
                unsigned u = bkt[base + j];
                int s  = u & 0xFFFFF;
                int dl = u >> 20;
                atomicAdd(&acc[(dl << 6) + f], g[((size_t)s << 6) + f]);
            }
        }
    }
    __syncthreads();
    int n0 = b << 8;
    for (int i = t; i < 16384; i += TPB) {
        int node = n0 + (i >> 6);
        if (node >= N) break;
        int ff = i & 63;
        float v = dinv[node] * (g[((size_t)node << 6) + ff] + acc[i]) + bias[ff];
        out[((size_t)node << 6) + ff] = fmaxf(v, 0.f);
    }
}

// ---------------- dense linears ----------------

__global__ __launch_bounds__(TPB) void k_lin3r(const float* __restrict__ q4,
                                               const float* __restrict__ W,
                                               const float* __restrict__ bias,
                                               float* __restrict__ h, int N) {
    int tid = blockIdx.x * TPB + threadIdx.x;
    int node = tid >> 6, f = tid & 63;
    if (node >= N) return;
    const float4 qv = ((const float4*)q4)[node];
    float v = qv.x * W[f] + qv.y * W[64 + f] + qv.z * W[128 + f] + bias[f];
    h[tid] = fmaxf(v, 0.f);
}

__global__ __launch_bounds__(TPB) void k_lin64(const float* __restrict__ h,
                                               const float* __restrict__ W,
                                               const float* __restrict__ dinv,
                                               float* __restrict__ g, int N) {
    __shared__ float Ws[4096];
    for (int i = threadIdx.x; i < 4096; i += TPB) Ws[i] = W[i];
    __syncthreads();
    int tid = blockIdx.x * TPB + threadIdx.x;
    int node = tid >> 6, f = tid & 63;
    if (node >= N) return;
    float xv = h[tid];
    float acc = 0.f;
#pragma unroll
    for (int k = 0; k < 64; ++k)
        acc = fmaf(__shfl(xv, k, 64), Ws[(k << 6) + f], acc);
    g[tid] = acc * dinv[node];
}

__global__ __launch_bounds__(TPB) void k_lin64_3(const float* __restrict__ h,
                                                 const float* __restrict__ W,
                                                 const float* __restrict__ dinv,
                                                 float* __restrict__ g34, int N) {
    int tid = blockIdx.x * TPB + threadIdx.x;
    int node = tid >> 6, k = tid & 63;
    if (node >= N) return;
    float hv = h[tid];
    float a0 = hv * W[k * 3 + 0];
    float a1 = hv * W[k * 3 + 1];
    float a2 = hv * W[k * 3 + 2];
#pragma unroll
    for (int off = 32; off > 0; off >>= 1) {
        a0 += __shfl_down(a0, off, 64);
        a1 += __shfl_down(a1, off, 64);
        a2 += __shfl_down(a2, off, 64);
    }
    if (k == 0) {
        float dv = dinv[node];
        g34[(size_t)node * 4 + 0] = a0 * dv;
        g34[(size_t)node * 4 + 1] = a1 * dv;
        g34[(size_t)node * 4 + 2] = a2 * dv;
        g34[(size_t)node * 4 + 3] = 0.f;
    }
}

extern "C" void kernel_launch(void* const* d_in, const int* in_sizes, int n_in,
                              void* d_out, int out_size, void* d_ws, size_t ws_size,
                              hipStream_t stream) {
    const float* x  = (const float*)d_in[0];
    const int*   ei = (const int*)  d_in[1];
    const float* W1 = (const float*)d_in[2];
    const float* b1 = (const float*)d_in[3];
    const float* W2 = (const float*)d_in[4];
    const float* b2 = (const float*)d_in[5];
    const float* W3 = (const float*)d_in[6];
    const float* b3 = (const float*)d_in[7];
    float* out = (float*)d_out;

    const int N = in_sizes[0] / 3;       // 100000
    const int E = in_sizes[1] / 2;       // 1600000
    const int* srcI = ei;
    const int* dstI = ei + E;

    // workspace layout (4-byte units):
    float*    ws     = (float*)d_ws;
    unsigned* gcount = (unsigned*)ws;                     // @0       [512]
    int*      cptr   = (int*)     (ws + 512);             // @512     [512]
    unsigned* gcur   = (unsigned*)(ws + 1024);            // @1024    [512]
    float*    dinv   = ws + 1536;                         // @1536    [N]
    unsigned* bkt    = (unsigned*)(ws + 1536 + N);        // [E]
    float*    xs4    = ws + 1536 + N + E;                 // [4N]
    float*    q4     = xs4 + (size_t)N * 4;               // [4N]
    float*    g      = q4  + (size_t)N * 4;               // [64N]  (also g34)
    float*    h      = g   + (size_t)N * 64;              // [64N]

    hipMemsetAsync(gcount, 0, 512 * sizeof(unsigned), stream);

    int gPlace = (E + CH - 1) / CH;                       // 196
    int gN64   = (int)(((size_t)N * 64) / TPB);           // 25000
    int gS3    = (N * 4 + TPB - 1) / TPB;

    // graph preprocessing: coarse bucket sort + dinv
    k_hist  <<<128,    TPB, 0, stream>>>(dstI, gcount, E);
    k_scan  <<<1,      512, 0, stream>>>(gcount, cptr, gcur, E);
    k_placeA<<<gPlace, TPB, 0, stream>>>(srcI, dstI, gcur, bkt, E);
    k_dinvB <<<NB,     TPB, 0, stream>>>(bkt, cptr, dinv, N);

    // layer 1: aggregate x (3-wide) first, then linear+relu
    k_scale3<<<gS3,  TPB, 0, stream>>>(x, dinv, xs4, N);
    k_agg3  <<<NB,   TPB, 0, stream>>>(bkt, cptr, xs4, dinv, q4, N);
    k_lin3r <<<gN64, TPB, 0, stream>>>(q4, W1, b1, h, N);

    // layer 2: linear, 64-wide aggregate (+bias+relu fused)
    k_lin64 <<<gN64, TPB, 0, stream>>>(h, W2, dinv, g, N);
    k_agg64 <<<NB,   TPB, 0, stream>>>(bkt, cptr, g, dinv, b2, h, N);

    // layer 3: linear to 3 (padded 4), aggregate 3-wide (+bias fused)
    k_lin64_3<<<gN64, TPB, 0, stream>>>(h, W3, dinv, g, N);
    k_agg3o  <<<NB,   TPB, 0, stream>>>(bkt, cptr, g, dinv, b3, out, N);
}

// Round 4
// 375.049 us; speedup vs baseline: 2.8025x; 2.8025x over previous
//
#include <hip/hip_runtime.h>

#define TPB 256
#define NB 391            // ceil(100000/256) coarse buckets of 256 nodes
#define CH 8192           // edges per k_placeA block

// ---------------- coarse histogram (LDS-privatized) ----------------

__global__ __launch_bounds__(TPB) void k_hist(const int* __restrict__ dst,
                                              unsigned* __restrict__ gcount, int E) {
    __shared__ unsigned c[512];
    int t = threadIdx.x;
    for (int b = t; b < 512; b += TPB) c[b] = 0;
    __syncthreads();
    int stride = gridDim.x * TPB;
    for (int i = blockIdx.x * TPB + t; i < E; i += stride)
        atomicAdd(&c[(unsigned)dst[i] >> 8], 1u);
    __syncthreads();
    for (int b = t; b < NB; b += TPB)
        if (c[b]) atomicAdd(&gcount[b], c[b]);
}

// ---------------- exclusive scan over NB buckets (1 block) ----------------

__global__ __launch_bounds__(512) void k_scan(const unsigned* __restrict__ gcount,
                                              int* __restrict__ cptr,
                                              unsigned* __restrict__ gcur, int E) {
    __shared__ unsigned s[512];
    int t = threadIdx.x;
    unsigned orig = (t < NB) ? gcount[t] : 0u;
    s[t] = orig;
    __syncthreads();
#pragma unroll
    for (int o = 1; o < 512; o <<= 1) {
        unsigned v = (t >= o) ? s[t - o] : 0u;
        __syncthreads();
        s[t] += v;
        __syncthreads();
    }
    if (t < NB) {
        unsigned ex = s[t] - orig;
        cptr[t] = (int)ex;
        gcur[t] = ex;
    }
    if (t == 0) cptr[NB] = E;
}

// ---------------- chunked coarse bucket sort, LDS-staged grouped writes ----
// packs each edge as  src | ((dst & 255) << 20)

__global__ __launch_bounds__(TPB) void k_placeA(const int* __restrict__ src,
                                                const int* __restrict__ dst,
                                                unsigned* __restrict__ gcur,
                                                unsigned* __restrict__ bkt, int E) {
    __shared__ unsigned val[CH];
    __shared__ unsigned short bid[CH];
    __shared__ unsigned cnt[512], loff[512], lcur[512], basev[512];
    __shared__ unsigned tsum[TPB];
    int t = threadIdx.x;
    int c0 = blockIdx.x * CH;
    int n = E - c0; if (n > CH) n = CH;

    for (int b = t; b < 512; b += TPB) { cnt[b] = 0; lcur[b] = 0; }
    __syncthreads();
    for (int i = t; i < n; i += TPB)
        atomicAdd(&cnt[(unsigned)dst[c0 + i] >> 8], 1u);
    __syncthreads();
    for (int b = t; b < NB; b += TPB)
        basev[b] = cnt[b] ? atomicAdd(&gcur[b], cnt[b]) : 0u;
    unsigned a0 = cnt[2 * t], a1 = cnt[2 * t + 1];
    tsum[t] = a0 + a1;
    __syncthreads();
#pragma unroll
    for (int o = 1; o < TPB; o <<= 1) {
        unsigned v = (t >= o) ? tsum[t - o] : 0u;
        __syncthreads();
        tsum[t] += v;
        __syncthreads();
    }
    unsigned ex = tsum[t] - (a0 + a1);
    loff[2 * t] = ex; loff[2 * t + 1] = ex + a0;
    __syncthreads();
    for (int i = t; i < n; i += TPB) {
        unsigned s = (unsigned)src[c0 + i];
        unsigned d = (unsigned)dst[c0 + i];
        unsigned b = d >> 8;
        unsigned r = atomicAdd(&lcur[b], 1u);
        unsigned slot = loff[b] + r;
        val[slot] = s | ((d & 255u) << 20);
        bid[slot] = (unsigned short)b;
    }
    __syncthreads();
    for (int i = t; i < n; i += TPB) {
        unsigned b = bid[i];
        bkt[basev[b] + ((unsigned)i - loff[b])] = val[i];
    }
}

// ---------------- fine sort within bucket -> per-node CSR + dinv ----------
// scattered writes confined to the bucket's contiguous 16KB region (L2-coalesced)

__global__ __launch_bounds__(TPB) void k_fine(const unsigned* __restrict__ bkt,
                                              const int* __restrict__ cptr,
                                              int* __restrict__ row_ptr,
                                              int* __restrict__ ssrc,
                                              float* __restrict__ dinv, int N, int E) {
    __shared__ unsigned cnt[256], sc[256], off[256];
    int t = threadIdx.x, b = blockIdx.x;
    cnt[t] = 0;
    __syncthreads();
    int p0 = cptr[b], p1 = cptr[b + 1];
    for (int i = p0 + t; i < p1; i += TPB)
        atomicAdd(&cnt[bkt[i] >> 20], 1u);
    __syncthreads();
    unsigned c = cnt[t];
    sc[t] = c;
    __syncthreads();
#pragma unroll
    for (int o = 1; o < 256; o <<= 1) {
        unsigned v = (t >= o) ? sc[t - o] : 0u;
        __syncthreads();
        sc[t] += v;
        __syncthreads();
    }
    unsigned ex = sc[t] - c;
    off[t] = ex;
    int node = (b << 8) + t;
    if (node < N) {
        row_ptr[node] = p0 + (int)ex;
        dinv[node] = rsqrtf((float)(c + 1u));   // +1 = self-loop
    }
    if (b == NB - 1 && t == 0) row_ptr[N] = E;
    __syncthreads();
    for (int i = p0 + t; i < p1; i += TPB) {
        unsigned u = bkt[i];
        unsigned r = atomicAdd(&off[u >> 20], 1u);
        ssrc[p0 + (int)r] = (int)(u & 0xFFFFFu);
    }
}

// ---------------- xs4 = dinv * x (padded to float4) ----------------

__global__ __launch_bounds__(TPB) void k_scale3(const float* __restrict__ x,
                                                const float* __restrict__ dinv,
                                                float* __restrict__ xs4, int N) {
    int tid = blockIdx.x * TPB + threadIdx.x;
    if (tid >= N * 4) return;
    int node = tid >> 2, c = tid & 3;
    xs4[tid] = (c < 3) ? x[node * 3 + c] * dinv[node] : 0.f;
}

// ---------------- 4-wide pull (quarter-wave per node): q4 = S x ------------

__global__ __launch_bounds__(TPB) void k_pull3x(const float* __restrict__ xs4,
                                                const int* __restrict__ row_ptr,
                                                const int* __restrict__ ssrc,
                                                const float* __restrict__ dinv,
                                                float* __restrict__ q4, int N) {
    int tid = blockIdx.x * TPB + threadIdx.x;
    int node = tid >> 2, c = tid & 3;
    if (node >= N) return;
    int beg = row_ptr[node], end = row_ptr[node + 1];
    float acc = xs4[tid];                       // self-loop
    int j = beg;
    for (; j + 3 < end; j += 4) {
        int s0 = ssrc[j], s1 = ssrc[j+1], s2 = ssrc[j+2], s3 = ssrc[j+3];
        acc += (xs4[(s0 << 2) + c] + xs4[(s1 << 2) + c])
             + (xs4[(s2 << 2) + c] + xs4[(s3 << 2) + c]);
    }
    for (; j < end; ++j) acc += xs4[(ssrc[j] << 2) + c];
    q4[tid] = dinv[node] * acc;
}

// ---------------- layer-3 pull with output epilogue ----------------

__global__ __launch_bounds__(TPB) void k_pull3o(const float* __restrict__ g34,
                                                const int* __restrict__ row_ptr,
                                                const int* __restrict__ ssrc,
                                                const float* __restrict__ dinv,
                                                const float* __restrict__ b3,
                                                float* __restrict__ out, int N) {
    int tid = blockIdx.x * TPB + threadIdx.x;
    int node = tid >> 2, c = tid & 3;
    if (node >= N) return;
    int beg = row_ptr[node], end = row_ptr[node + 1];
    float acc = g34[tid];                       // self-loop
    int j = beg;
    for (; j + 3 < end; j += 4) {
        int s0 = ssrc[j], s1 = ssrc[j+1], s2 = ssrc[j+2], s3 = ssrc[j+3];
        acc += (g34[(s0 << 2) + c] + g34[(s1 << 2) + c])
             + (g34[(s2 << 2) + c] + g34[(s3 << 2) + c]);
    }
    for (; j < end; ++j) acc += g34[(ssrc[j] << 2) + c];
    if (c < 3) out[(size_t)node * 3 + c] = dinv[node] * acc + b3[c];
}

// ---------------- 64-wide pull (wave per node), fused bias+relu ------------

__global__ __launch_bounds__(TPB) void k_pull64(const float* __restrict__ g,
                                                const int* __restrict__ row_ptr,
                                                const int* __restrict__ ssrc,
                                                const float* __restrict__ dinv,
                                                const float* __restrict__ bias,
                                                float* __restrict__ out, int N) {
    int tid = blockIdx.x * TPB + threadIdx.x;
    int node = tid >> 6, f = tid & 63;
    if (node >= N) return;
    int beg = row_ptr[node], end = row_ptr[node + 1];
    float acc = g[tid];                         // self-loop
    int j = beg;
    for (; j + 3 < end; j += 4) {
        int s0 = ssrc[j], s1 = ssrc[j+1], s2 = ssrc[j+2], s3 = ssrc[j+3];
        float v0 = g[((size_t)s0 << 6) + f];
        float v1 = g[((size_t)s1 << 6) + f];
        float v2 = g[((size_t)s2 << 6) + f];
        float v3 = g[((size_t)s3 << 6) + f];
        acc += (v0 + v1) + (v2 + v3);
    }
    for (; j < end; ++j) acc += g[((size_t)ssrc[j] << 6) + f];
    float v = acc * dinv[node] + bias[f];
    out[tid] = fmaxf(v, 0.f);
}

// ---------------- dense linears ----------------

__global__ __launch_bounds__(TPB) void k_lin3r(const float* __restrict__ q4,
                                               const float* __restrict__ W,
                                               const float* __restrict__ bias,
                                               float* __restrict__ h, int N) {
    int tid = blockIdx.x * TPB + threadIdx.x;
    int node = tid >> 6, f = tid & 63;
    if (node >= N) return;
    const float4 qv = ((const float4*)q4)[node];
    float v = qv.x * W[f] + qv.y * W[64 + f] + qv.z * W[128 + f] + bias[f];
    h[tid] = fmaxf(v, 0.f);
}

__global__ __launch_bounds__(TPB) void k_lin64(const float* __restrict__ h,
                                               const float* __restrict__ W,
                                               const float* __restrict__ dinv,
                                               float* __restrict__ g, int N) {
    __shared__ float Ws[4096];
    for (int i = threadIdx.x; i < 4096; i += TPB) Ws[i] = W[i];
    __syncthreads();
    int tid = blockIdx.x * TPB + threadIdx.x;
    int node = tid >> 6, f = tid & 63;
    if (node >= N) return;
    float xv = h[tid];
    float acc = 0.f;
#pragma unroll
    for (int k = 0; k < 64; ++k)
        acc = fmaf(__shfl(xv, k, 64), Ws[(k << 6) + f], acc);
    g[tid] = acc * dinv[node];
}

__global__ __launch_bounds__(TPB) void k_lin64_3(const float* __restrict__ h,
                                                 const float* __restrict__ W,
                                                 const float* __restrict__ dinv,
                                                 float* __restrict__ g34, int N) {
    int tid = blockIdx.x * TPB + threadIdx.x;
    int node = tid >> 6, k = tid & 63;
    if (node >= N) return;
    float hv = h[tid];
    float a0 = hv * W[k * 3 + 0];
    float a1 = hv * W[k * 3 + 1];
    float a2 = hv * W[k * 3 + 2];
#pragma unroll
    for (int off = 32; off > 0; off >>= 1) {
        a0 += __shfl_down(a0, off, 64);
        a1 += __shfl_down(a1, off, 64);
        a2 += __shfl_down(a2, off, 64);
    }
    if (k == 0) {
        float dv = dinv[node];
        g34[(size_t)node * 4 + 0] = a0 * dv;
        g34[(size_t)node * 4 + 1] = a1 * dv;
        g34[(size_t)node * 4 + 2] = a2 * dv;
        g34[(size_t)node * 4 + 3] = 0.f;
    }
}

extern "C" void kernel_launch(void* const* d_in, const int* in_sizes, int n_in,
                              void* d_out, int out_size, void* d_ws, size_t ws_size,
                              hipStream_t stream) {
    const float* x  = (const float*)d_in[0];
    const int*   ei = (const int*)  d_in[1];
    const float* W1 = (const float*)d_in[2];
    const float* b1 = (const float*)d_in[3];
    const float* W2 = (const float*)d_in[4];
    const float* b2 = (const float*)d_in[5];
    const float* W3 = (const float*)d_in[6];
    const float* b3 = (const float*)d_in[7];
    float* out = (float*)d_out;

    const int N = in_sizes[0] / 3;       // 100000
    const int E = in_sizes[1] / 2;       // 1600000
    const int* srcI = ei;
    const int* dstI = ei + E;

    // workspace layout (4-byte units); bkt aliases g (bkt dead before g written)
    float*    ws      = (float*)d_ws;
    unsigned* gcount  = (unsigned*)ws;                      // @0      [512]
    int*      cptr    = (int*)     (ws + 512);              // @512    [512]
    unsigned* gcur    = (unsigned*)(ws + 1024);             // @1024   [512]
    int*      row_ptr = (int*)     (ws + 1536);             // [N+1] (pad to N+4)
    float*    dinv    = ws + 1536 + (N + 4);                // [N]
    int*      ssrc    = (int*)     (dinv + N);              // [E]
    float*    xs4     = (float*)(ssrc + E);                 // [4N]
    float*    q4      = xs4 + (size_t)N * 4;                // [4N]  (also g34)
    float*    g       = q4  + (size_t)N * 4;                // [64N]
    float*    h       = g   + (size_t)N * 64;               // [64N]
    unsigned* bkt     = (unsigned*)g;                       // [E] alias

    hipMemsetAsync(gcount, 0, 512 * sizeof(unsigned), stream);

    int gPlace = (E + CH - 1) / CH;                         // 196
    int gN64   = (int)(((size_t)N * 64) / TPB);             // 25000
    int gS3    = (N * 4 + TPB - 1) / TPB;                   // 1563

    // graph preprocessing: two-phase counting sort -> per-node CSR + dinv
    k_hist  <<<128,    TPB, 0, stream>>>(dstI, gcount, E);
    k_scan  <<<1,      512, 0, stream>>>(gcount, cptr, gcur, E);
    k_placeA<<<gPlace, TPB, 0, stream>>>(srcI, dstI, gcur, bkt, E);
    k_fine  <<<NB,     TPB, 0, stream>>>(bkt, cptr, row_ptr, ssrc, dinv, N, E);

    // layer 1: aggregate x (4-wide padded), then linear+relu
    k_scale3<<<gS3,  TPB, 0, stream>>>(x, dinv, xs4, N);
    k_pull3x<<<gS3,  TPB, 0, stream>>>(xs4, row_ptr, ssrc, dinv, q4, N);
    k_lin3r <<<gN64, TPB, 0, stream>>>(q4, W1, b1, h, N);

    // layer 2: linear, 64-wide pull (+bias+relu fused)
    k_lin64 <<<gN64, TPB, 0, stream>>>(h, W2, dinv, g, N);
    k_pull64<<<gN64, TPB, 0, stream>>>(g, row_ptr, ssrc, dinv, b2, h, N);

    // layer 3: linear to 3 (padded 4), pull 3-wide (+bias fused)
    k_lin64_3<<<gN64, TPB, 0, stream>>>(h, W3, dinv, q4, N);
    k_pull3o <<<gS3,  TPB, 0, stream>>>(q4, row_ptr, ssrc, dinv, b3, out, N);
}

// Round 5
// 295.922 us; speedup vs baseline: 3.5518x; 1.2674x over previous
//
#include <hip/hip_runtime.h>

#define TPB 256
#define NB 391            // ceil(100000/256) coarse buckets of 256 nodes
#define CH 8192           // edges per k_placeA block

// ---------------- coarse histogram (LDS-privatized) ----------------

__global__ __launch_bounds__(TPB) void k_hist(const int* __restrict__ dst,
                                              unsigned* __restrict__ gcount, int E) {
    __shared__ unsigned c[512];
    int t = threadIdx.x;
    for (int b = t; b < 512; b += TPB) c[b] = 0;
    __syncthreads();
    int stride = gridDim.x * TPB;
    for (int i = blockIdx.x * TPB + t; i < E; i += stride)
        atomicAdd(&c[(unsigned)dst[i] >> 8], 1u);
    __syncthreads();
    for (int b = t; b < NB; b += TPB)
        if (c[b]) atomicAdd(&gcount[b], c[b]);
}

// ---------------- exclusive scan over NB buckets (1 block) ----------------

__global__ __launch_bounds__(512) void k_scan(const unsigned* __restrict__ gcount,
                                              int* __restrict__ cptr,
                                              unsigned* __restrict__ gcur, int E) {
    __shared__ unsigned s[512];
    int t = threadIdx.x;
    unsigned orig = (t < NB) ? gcount[t] : 0u;
    s[t] = orig;
    __syncthreads();
#pragma unroll
    for (int o = 1; o < 512; o <<= 1) {
        unsigned v = (t >= o) ? s[t - o] : 0u;
        __syncthreads();
        s[t] += v;
        __syncthreads();
    }
    if (t < NB) {
        unsigned ex = s[t] - orig;
        cptr[t] = (int)ex;
        gcur[t] = ex;
    }
    if (t == 0) cptr[NB] = E;
}

// ---------------- chunked coarse bucket sort, LDS-staged grouped writes ----
// packs each edge as  src | ((dst & 255) << 20)

__global__ __launch_bounds__(TPB) void k_placeA(const int* __restrict__ src,
                                                const int* __restrict__ dst,
                                                unsigned* __restrict__ gcur,
                                                unsigned* __restrict__ bkt, int E) {
    __shared__ unsigned val[CH];
    __shared__ unsigned short bid[CH];
    __shared__ unsigned cnt[512], loff[512], lcur[512], basev[512];
    __shared__ unsigned tsum[TPB];
    int t = threadIdx.x;
    int c0 = blockIdx.x * CH;
    int n = E - c0; if (n > CH) n = CH;

    for (int b = t; b < 512; b += TPB) { cnt[b] = 0; lcur[b] = 0; }
    __syncthreads();
    for (int i = t; i < n; i += TPB)
        atomicAdd(&cnt[(unsigned)dst[c0 + i] >> 8], 1u);
    __syncthreads();
    for (int b = t; b < NB; b += TPB)
        basev[b] = cnt[b] ? atomicAdd(&gcur[b], cnt[b]) : 0u;
    unsigned a0 = cnt[2 * t], a1 = cnt[2 * t + 1];
    tsum[t] = a0 + a1;
    __syncthreads();
#pragma unroll
    for (int o = 1; o < TPB; o <<= 1) {
        unsigned v = (t >= o) ? tsum[t - o] : 0u;
        __syncthreads();
        tsum[t] += v;
        __syncthreads();
    }
    unsigned ex = tsum[t] - (a0 + a1);
    loff[2 * t] = ex; loff[2 * t + 1] = ex + a0;
    __syncthreads();
    for (int i = t; i < n; i += TPB) {
        unsigned s = (unsigned)src[c0 + i];
        unsigned d = (unsigned)dst[c0 + i];
        unsigned b = d >> 8;
        unsigned r = atomicAdd(&lcur[b], 1u);
        unsigned slot = loff[b] + r;
        val[slot] = s | ((d & 255u) << 20);
        bid[slot] = (unsigned short)b;
    }
    __syncthreads();
    for (int i = t; i < n; i += TPB) {
        unsigned b = bid[i];
        bkt[basev[b] + ((unsigned)i - loff[b])] = val[i];
    }
}

// ---------------- fine sort within bucket -> per-node CSR + dinv ----------

__global__ __launch_bounds__(TPB) void k_fine(const unsigned* __restrict__ bkt,
                                              const int* __restrict__ cptr,
                                              int* __restrict__ row_ptr,
                                              int* __restrict__ ssrc,
                                              float* __restrict__ dinv, int N, int E) {
    __shared__ unsigned cnt[256], sc[256], off[256];
    int t = threadIdx.x, b = blockIdx.x;
    cnt[t] = 0;
    __syncthreads();
    int p0 = cptr[b], p1 = cptr[b + 1];
    for (int i = p0 + t; i < p1; i += TPB)
        atomicAdd(&cnt[bkt[i] >> 20], 1u);
    __syncthreads();
    unsigned c = cnt[t];
    sc[t] = c;
    __syncthreads();
#pragma unroll
    for (int o = 1; o < 256; o <<= 1) {
        unsigned v = (t >= o) ? sc[t - o] : 0u;
        __syncthreads();
        sc[t] += v;
        __syncthreads();
    }
    unsigned ex = sc[t] - c;
    off[t] = ex;
    int node = (b << 8) + t;
    if (node < N) {
        row_ptr[node] = p0 + (int)ex;
        dinv[node] = rsqrtf((float)(c + 1u));   // +1 = self-loop
    }
    if (b == NB - 1 && t == 0) row_ptr[N] = E;
    __syncthreads();
    for (int i = p0 + t; i < p1; i += TPB) {
        unsigned u = bkt[i];
        unsigned r = atomicAdd(&off[u >> 20], 1u);
        ssrc[p0 + (int)r] = (int)(u & 0xFFFFFu);
    }
}

// ---------------- xs4 = dinv * x (padded to float4) ----------------

__global__ __launch_bounds__(TPB) void k_scale3(const float* __restrict__ x,
                                                const float* __restrict__ dinv,
                                                float* __restrict__ xs4, int N) {
    int tid = blockIdx.x * TPB + threadIdx.x;
    if (tid >= N * 4) return;
    int node = tid >> 2, c = tid & 3;
    xs4[tid] = (c < 3) ? x[node * 3 + c] * dinv[node] : 0.f;
}

// ---------------- 4-wide pull (quarter-wave per node): q4 = S x ------------

__global__ __launch_bounds__(TPB) void k_pull3x(const float* __restrict__ xs4,
                                                const int* __restrict__ row_ptr,
                                                const int* __restrict__ ssrc,
                                                const float* __restrict__ dinv,
                                                float* __restrict__ q4, int N) {
    int tid = blockIdx.x * TPB + threadIdx.x;
    int node = tid >> 2, c = tid & 3;
    if (node >= N) return;
    int beg = row_ptr[node], end = row_ptr[node + 1];
    float acc = xs4[tid];                       // self-loop
    int j = beg;
    for (; j + 3 < end; j += 4) {
        int s0 = ssrc[j], s1 = ssrc[j+1], s2 = ssrc[j+2], s3 = ssrc[j+3];
        acc += (xs4[(s0 << 2) + c] + xs4[(s1 << 2) + c])
             + (xs4[(s2 << 2) + c] + xs4[(s3 << 2) + c]);
    }
    for (; j < end; ++j) acc += xs4[(ssrc[j] << 2) + c];
    q4[tid] = dinv[node] * acc;
}

// ---------------- layer-3 pull with output epilogue ----------------

__global__ __launch_bounds__(TPB) void k_pull3o(const float* __restrict__ g34,
                                                const int* __restrict__ row_ptr,
                                                const int* __restrict__ ssrc,
                                                const float* __restrict__ dinv,
                                                const float* __restrict__ b3,
                                                float* __restrict__ out, int N) {
    int tid = blockIdx.x * TPB + threadIdx.x;
    int node = tid >> 2, c = tid & 3;
    if (node >= N) return;
    int beg = row_ptr[node], end = row_ptr[node + 1];
    float acc = g34[tid];                       // self-loop
    int j = beg;
    for (; j + 3 < end; j += 4) {
        int s0 = ssrc[j], s1 = ssrc[j+1], s2 = ssrc[j+2], s3 = ssrc[j+3];
        acc += (g34[(s0 << 2) + c] + g34[(s1 << 2) + c])
             + (g34[(s2 << 2) + c] + g34[(s3 << 2) + c]);
    }
    for (; j < end; ++j) acc += g34[(ssrc[j] << 2) + c];
    if (c < 3) out[(size_t)node * 3 + c] = dinv[node] * acc + b3[c];
}

// ---------------- 64-wide pull (wave per node), fused bias+relu ------------

__global__ __launch_bounds__(TPB) void k_pull64(const float* __restrict__ g,
                                                const int* __restrict__ row_ptr,
                                                const int* __restrict__ ssrc,
                                                const float* __restrict__ dinv,
                                                const float* __restrict__ bias,
                                                float* __restrict__ out, int N) {
    int tid = blockIdx.x * TPB + threadIdx.x;
    int node = tid >> 6, f = tid & 63;
    if (node >= N) return;
    int beg = row_ptr[node], end = row_ptr[node + 1];
    float acc = g[tid];                         // self-loop
    int j = beg;
    for (; j + 3 < end; j += 4) {
        int s0 = ssrc[j], s1 = ssrc[j+1], s2 = ssrc[j+2], s3 = ssrc[j+3];
        float v0 = g[((size_t)s0 << 6) + f];
        float v1 = g[((size_t)s1 << 6) + f];
        float v2 = g[((size_t)s2 << 6) + f];
        float v3 = g[((size_t)s3 << 6) + f];
        acc += (v0 + v1) + (v2 + v3);
    }
    for (; j < end; ++j) acc += g[((size_t)ssrc[j] << 6) + f];
    float v = acc * dinv[node] + bias[f];
    out[tid] = fmaxf(v, 0.f);
}

// ---------------- dense linears (thread-per-node register GEMM) ------------
// W rows read at wave-uniform addresses -> scalar (s_load) path, VALU does
// only the 4096 FMAs. acc[64] fully constant-indexed (inner loops unrolled).

__global__ __launch_bounds__(TPB) void k_lin64n(const float* __restrict__ h,
                                                const float* __restrict__ W,
                                                const float* __restrict__ dinv,
                                                float* __restrict__ g, int N) {
    int node = blockIdx.x * TPB + threadIdx.x;
    if (node >= N) return;
    const float4* hp = (const float4*)(h + ((size_t)node << 6));
    float acc[64];
#pragma unroll
    for (int f = 0; f < 64; ++f) acc[f] = 0.f;
    for (int kb = 0; kb < 16; ++kb) {
        float4 hv = hp[kb];
        const float* Wr = W + (__builtin_amdgcn_readfirstlane(kb) << 8);
#pragma unroll
        for (int f = 0; f < 64; ++f) {
            float a = acc[f];
            a = fmaf(hv.x, Wr[f],        a);
            a = fmaf(hv.y, Wr[64  + f],  a);
            a = fmaf(hv.z, Wr[128 + f],  a);
            a = fmaf(hv.w, Wr[192 + f],  a);
            acc[f] = a;
        }
    }
    float dv = dinv[node];
    float4* gp = (float4*)(g + ((size_t)node << 6));
#pragma unroll
    for (int i = 0; i < 16; ++i) {
        float4 v;
        v.x = acc[4*i+0] * dv;
        v.y = acc[4*i+1] * dv;
        v.z = acc[4*i+2] * dv;
        v.w = acc[4*i+3] * dv;
        gp[i] = v;
    }
}

__global__ __launch_bounds__(TPB) void k_lin64_3n(const float* __restrict__ h,
                                                  const float* __restrict__ W,
                                                  const float* __restrict__ dinv,
                                                  float* __restrict__ g34, int N) {
    int node = blockIdx.x * TPB + threadIdx.x;
    if (node >= N) return;
    const float4* hp = (const float4*)(h + ((size_t)node << 6));
    float a0 = 0.f, a1 = 0.f, a2 = 0.f;
    for (int kb = 0; kb < 16; ++kb) {
        float4 hv = hp[kb];
        const float* Wr = W + __builtin_amdgcn_readfirstlane(kb) * 12;
        a0 = fmaf(hv.x, Wr[0],  a0); a1 = fmaf(hv.x, Wr[1],  a1); a2 = fmaf(hv.x, Wr[2],  a2);
        a0 = fmaf(hv.y, Wr[3],  a0); a1 = fmaf(hv.y, Wr[4],  a1); a2 = fmaf(hv.y, Wr[5],  a2);
        a0 = fmaf(hv.z, Wr[6],  a0); a1 = fmaf(hv.z, Wr[7],  a1); a2 = fmaf(hv.z, Wr[8],  a2);
        a0 = fmaf(hv.w, Wr[9],  a0); a1 = fmaf(hv.w, Wr[10], a1); a2 = fmaf(hv.w, Wr[11], a2);
    }
    float dv = dinv[node];
    float4 v;
    v.x = a0 * dv; v.y = a1 * dv; v.z = a2 * dv; v.w = 0.f;
    ((float4*)g34)[node] = v;
}

__global__ __launch_bounds__(TPB) void k_lin3r(const float* __restrict__ q4,
                                               const float* __restrict__ W,
                                               const float* __restrict__ bias,
                                               float* __restrict__ h, int N) {
    int tid = blockIdx.x * TPB + threadIdx.x;
    int node = tid >> 6, f = tid & 63;
    if (node >= N) return;
    const float4 qv = ((const float4*)q4)[node];
    float v = qv.x * W[f] + qv.y * W[64 + f] + qv.z * W[128 + f] + bias[f];
    h[tid] = fmaxf(v, 0.f);
}

extern "C" void kernel_launch(void* const* d_in, const int* in_sizes, int n_in,
                              void* d_out, int out_size, void* d_ws, size_t ws_size,
                              hipStream_t stream) {
    const float* x  = (const float*)d_in[0];
    const int*   ei = (const int*)  d_in[1];
    const float* W1 = (const float*)d_in[2];
    const float* b1 = (const float*)d_in[3];
    const float* W2 = (const float*)d_in[4];
    const float* b2 = (const float*)d_in[5];
    const float* W3 = (const float*)d_in[6];
    const float* b3 = (const float*)d_in[7];
    float* out = (float*)d_out;

    const int N = in_sizes[0] / 3;       // 100000
    const int E = in_sizes[1] / 2;       // 1600000
    const int* srcI = ei;
    const int* dstI = ei + E;

    // workspace layout (4-byte units); bkt aliases g (bkt dead before g written)
    float*    ws      = (float*)d_ws;
    unsigned* gcount  = (unsigned*)ws;                      // @0      [512]
    int*      cptr    = (int*)     (ws + 512);              // @512    [512]
    unsigned* gcur    = (unsigned*)(ws + 1024);             // @1024   [512]
    int*      row_ptr = (int*)     (ws + 1536);             // [N+1] (pad to N+4)
    float*    dinv    = ws + 1536 + (N + 4);                // [N]
    int*      ssrc    = (int*)     (dinv + N);              // [E]
    float*    xs4     = (float*)(ssrc + E);                 // [4N]
    float*    q4      = xs4 + (size_t)N * 4;                // [4N]  (also g34)
    float*    g       = q4  + (size_t)N * 4;                // [64N]
    float*    h       = g   + (size_t)N * 64;               // [64N]
    unsigned* bkt     = (unsigned*)g;                       // [E] alias

    hipMemsetAsync(gcount, 0, 512 * sizeof(unsigned), stream);

    int gPlace = (E + CH - 1) / CH;                         // 196
    int gN64   = (int)(((size_t)N * 64) / TPB);             // 25000
    int gS3    = (N * 4 + TPB - 1) / TPB;                   // 1563
    int gN     = (N + TPB - 1) / TPB;                       // 391

    // graph preprocessing: two-phase counting sort -> per-node CSR + dinv
    k_hist  <<<128,    TPB, 0, stream>>>(dstI, gcount, E);
    k_scan  <<<1,      512, 0, stream>>>(gcount, cptr, gcur, E);
    k_placeA<<<gPlace, TPB, 0, stream>>>(srcI, dstI, gcur, bkt, E);
    k_fine  <<<NB,     TPB, 0, stream>>>(bkt, cptr, row_ptr, ssrc, dinv, N, E);

    // layer 1: aggregate x (4-wide padded), then linear+relu
    k_scale3<<<gS3,  TPB, 0, stream>>>(x, dinv, xs4, N);
    k_pull3x<<<gS3,  TPB, 0, stream>>>(xs4, row_ptr, ssrc, dinv, q4, N);
    k_lin3r <<<gN64, TPB, 0, stream>>>(q4, W1, b1, h, N);

    // layer 2: linear (thread-per-node register GEMM), 64-wide pull
    k_lin64n<<<gN,   TPB, 0, stream>>>(h, W2, dinv, g, N);
    k_pull64<<<gN64, TPB, 0, stream>>>(g, row_ptr, ssrc, dinv, b2, h, N);

    // layer 3: linear to 3 (padded 4), pull 3-wide (+bias fused)
    k_lin64_3n<<<gN,  TPB, 0, stream>>>(h, W3, dinv, q4, N);
    k_pull3o  <<<gS3, TPB, 0, stream>>>(q4, row_ptr, ssrc, dinv, b3, out, N);
}

// Round 6
// 291.293 us; speedup vs baseline: 3.6082x; 1.0159x over previous
//
#include <hip/hip_runtime.h>

#define TPB 256
#define NB 391            // ceil(100000/256) coarse buckets of 256 nodes
#define CH 8192           // edges per k_placeA block

// ---------------- coarse histogram (LDS-privatized) ----------------

__global__ __launch_bounds__(TPB) void k_hist(const int* __restrict__ dst,
                                              unsigned* __restrict__ gcount, int E) {
    __shared__ unsigned c[512];
    int t = threadIdx.x;
    for (int b = t; b < 512; b += TPB) c[b] = 0;
    __syncthreads();
    int stride = gridDim.x * TPB;
    for (int i = blockIdx.x * TPB + t; i < E; i += stride)
        atomicAdd(&c[(unsigned)dst[i] >> 8], 1u);
    __syncthreads();
    for (int b = t; b < NB; b += TPB)
        if (c[b]) atomicAdd(&gcount[b], c[b]);
}

// ---------------- exclusive scan over NB buckets (1 block) ----------------

__global__ __launch_bounds__(512) void k_scan(const unsigned* __restrict__ gcount,
                                              int* __restrict__ cptr,
                                              unsigned* __restrict__ gcur, int E) {
    __shared__ unsigned s[512];
    int t = threadIdx.x;
    unsigned orig = (t < NB) ? gcount[t] : 0u;
    s[t] = orig;
    __syncthreads();
#pragma unroll
    for (int o = 1; o < 512; o <<= 1) {
        unsigned v = (t >= o) ? s[t - o] : 0u;
        __syncthreads();
        s[t] += v;
        __syncthreads();
    }
    if (t < NB) {
        unsigned ex = s[t] - orig;
        cptr[t] = (int)ex;
        gcur[t] = ex;
    }
    if (t == 0) cptr[NB] = E;
}

// ---------------- chunked coarse bucket sort, LDS-staged grouped writes ----
// packs each edge as  src | ((dst & 255) << 20)

__global__ __launch_bounds__(TPB) void k_placeA(const int* __restrict__ src,
                                                const int* __restrict__ dst,
                                                unsigned* __restrict__ gcur,
                                                unsigned* __restrict__ bkt, int E) {
    __shared__ unsigned val[CH];
    __shared__ unsigned short bid[CH];
    __shared__ unsigned cnt[512], loff[512], lcur[512], basev[512];
    __shared__ unsigned tsum[TPB];
    int t = threadIdx.x;
    int c0 = blockIdx.x * CH;
    int n = E - c0; if (n > CH) n = CH;

    for (int b = t; b < 512; b += TPB) { cnt[b] = 0; lcur[b] = 0; }
    __syncthreads();
    for (int i = t; i < n; i += TPB)
        atomicAdd(&cnt[(unsigned)dst[c0 + i] >> 8], 1u);
    __syncthreads();
    for (int b = t; b < NB; b += TPB)
        basev[b] = cnt[b] ? atomicAdd(&gcur[b], cnt[b]) : 0u;
    unsigned a0 = cnt[2 * t], a1 = cnt[2 * t + 1];
    tsum[t] = a0 + a1;
    __syncthreads();
#pragma unroll
    for (int o = 1; o < TPB; o <<= 1) {
        unsigned v = (t >= o) ? tsum[t - o] : 0u;
        __syncthreads();
        tsum[t] += v;
        __syncthreads();
    }
    unsigned ex = tsum[t] - (a0 + a1);
    loff[2 * t] = ex; loff[2 * t + 1] = ex + a0;
    __syncthreads();
    for (int i = t; i < n; i += TPB) {
        unsigned s = (unsigned)src[c0 + i];
        unsigned d = (unsigned)dst[c0 + i];
        unsigned b = d >> 8;
        unsigned r = atomicAdd(&lcur[b], 1u);
        unsigned slot = loff[b] + r;
        val[slot] = s | ((d & 255u) << 20);
        bid[slot] = (unsigned short)b;
    }
    __syncthreads();
    for (int i = t; i < n; i += TPB) {
        unsigned b = bid[i];
        bkt[basev[b] + ((unsigned)i - loff[b])] = val[i];
    }
}

// ---------------- fine sort within bucket -> per-node CSR + dinv ----------

__global__ __launch_bounds__(TPB) void k_fine(const unsigned* __restrict__ bkt,
                                              const int* __restrict__ cptr,
                                              int* __restrict__ row_ptr,
                                              int* __restrict__ ssrc,
                                              float* __restrict__ dinv, int N, int E) {
    __shared__ unsigned cnt[256], sc[256], off[256];
    int t = threadIdx.x, b = blockIdx.x;
    cnt[t] = 0;
    __syncthreads();
    int p0 = cptr[b], p1 = cptr[b + 1];
    for (int i = p0 + t; i < p1; i += TPB)
        atomicAdd(&cnt[bkt[i] >> 20], 1u);
    __syncthreads();
    unsigned c = cnt[t];
    sc[t] = c;
    __syncthreads();
#pragma unroll
    for (int o = 1; o < 256; o <<= 1) {
        unsigned v = (t >= o) ? sc[t - o] : 0u;
        __syncthreads();
        sc[t] += v;
        __syncthreads();
    }
    unsigned ex = sc[t] - c;
    off[t] = ex;
    int node = (b << 8) + t;
    if (node < N) {
        row_ptr[node] = p0 + (int)ex;
        dinv[node] = rsqrtf((float)(c + 1u));   // +1 = self-loop
    }
    if (b == NB - 1 && t == 0) row_ptr[N] = E;
    __syncthreads();
    for (int i = p0 + t; i < p1; i += TPB) {
        unsigned u = bkt[i];
        unsigned r = atomicAdd(&off[u >> 20], 1u);
        ssrc[p0 + (int)r] = (int)(u & 0xFFFFFu);
    }
}

// ---------------- xs4 = dinv * x (padded to float4) ----------------

__global__ __launch_bounds__(TPB) void k_scale3(const float* __restrict__ x,
                                                const float* __restrict__ dinv,
                                                float* __restrict__ xs4, int N) {
    int tid = blockIdx.x * TPB + threadIdx.x;
    if (tid >= N * 4) return;
    int node = tid >> 2, c = tid & 3;
    xs4[tid] = (c < 3) ? x[node * 3 + c] * dinv[node] : 0.f;
}

// ---------------- layer 1 fused: pull (4 lanes/node) + linear 3->64 + relu -

__global__ __launch_bounds__(TPB) void k_l1(const float* __restrict__ xs4,
                                            const int* __restrict__ row_ptr,
                                            const int* __restrict__ ssrc,
                                            const float* __restrict__ dinv,
                                            const float* __restrict__ W1,
                                            const float* __restrict__ b1,
                                            float* __restrict__ h, int N) {
    int tid = blockIdx.x * TPB + threadIdx.x;
    int node = tid >> 2, c = tid & 3;
    if (node >= N) return;
    int beg = row_ptr[node], end = row_ptr[node + 1];
    float acc = xs4[tid];                       // self-loop (c=3 lane carries 0)
    int j = beg;
    for (; j + 3 < end; j += 4) {
        int s0 = ssrc[j], s1 = ssrc[j+1], s2 = ssrc[j+2], s3 = ssrc[j+3];
        acc += (xs4[(s0 << 2) + c] + xs4[(s1 << 2) + c])
             + (xs4[(s2 << 2) + c] + xs4[(s3 << 2) + c]);
    }
    for (; j < end; ++j) acc += xs4[(ssrc[j] << 2) + c];
    acc *= dinv[node];
    // lanes c=0..2 of this 4-lane group hold q0..q2; broadcast within group
    int base = (threadIdx.x & 63) & ~3;
    float q0 = __shfl(acc, base + 0, 64);
    float q1 = __shfl(acc, base + 1, 64);
    float q2 = __shfl(acc, base + 2, 64);
    // lane c computes features f = c*16 .. c*16+15
    const float* Wc = W1 + (c << 4);
    const float* bc = b1 + (c << 4);
    float4* hp = (float4*)(h + ((size_t)node << 6) + (c << 4));
#pragma unroll
    for (int i = 0; i < 4; ++i) {
        float4 v;
        v.x = fmaf(q0, Wc[4*i+0], fmaf(q1, Wc[64+4*i+0], fmaf(q2, Wc[128+4*i+0], bc[4*i+0])));
        v.y = fmaf(q0, Wc[4*i+1], fmaf(q1, Wc[64+4*i+1], fmaf(q2, Wc[128+4*i+1], bc[4*i+1])));
        v.z = fmaf(q0, Wc[4*i+2], fmaf(q1, Wc[64+4*i+2], fmaf(q2, Wc[128+4*i+2], bc[4*i+2])));
        v.w = fmaf(q0, Wc[4*i+3], fmaf(q1, Wc[64+4*i+3], fmaf(q2, Wc[128+4*i+3], bc[4*i+3])));
        v.x = fmaxf(v.x, 0.f); v.y = fmaxf(v.y, 0.f);
        v.z = fmaxf(v.z, 0.f); v.w = fmaxf(v.w, 0.f);
        hp[i] = v;
    }
}

// ---------------- layer-3 pull with output epilogue ----------------

__global__ __launch_bounds__(TPB) void k_pull3o(const float* __restrict__ g34,
                                                const int* __restrict__ row_ptr,
                                                const int* __restrict__ ssrc,
                                                const float* __restrict__ dinv,
                                                const float* __restrict__ b3,
                                                float* __restrict__ out, int N) {
    int tid = blockIdx.x * TPB + threadIdx.x;
    int node = tid >> 2, c = tid & 3;
    if (node >= N) return;
    int beg = row_ptr[node], end = row_ptr[node + 1];
    float acc = g34[tid];                       // self-loop
    int j = beg;
    for (; j + 3 < end; j += 4) {
        int s0 = ssrc[j], s1 = ssrc[j+1], s2 = ssrc[j+2], s3 = ssrc[j+3];
        acc += (g34[(s0 << 2) + c] + g34[(s1 << 2) + c])
             + (g34[(s2 << 2) + c] + g34[(s3 << 2) + c]);
    }
    for (; j < end; ++j) acc += g34[(ssrc[j] << 2) + c];
    if (c < 3) out[(size_t)node * 3 + c] = dinv[node] * acc + b3[c];
}

// ---------------- 64-wide pull: 16 lanes/node, float4 per lane -------------
// 4-edge unroll -> 16 edges (64 dwordx4) in flight per wave

__global__ __launch_bounds__(TPB) void k_pull64q(const float4* __restrict__ g4,
                                                 const int* __restrict__ row_ptr,
                                                 const int* __restrict__ ssrc,
                                                 const float* __restrict__ dinv,
                                                 const float4* __restrict__ bias4,
                                                 float4* __restrict__ out4, int N) {
    int tid = blockIdx.x * TPB + threadIdx.x;
    int node = tid >> 4, q = tid & 15;
    if (node >= N) return;
    int beg = row_ptr[node], end = row_ptr[node + 1];
    float4 a = g4[((size_t)node << 4) + q];     // self-loop
    int j = beg;
    for (; j + 3 < end; j += 4) {
        int s0 = ssrc[j], s1 = ssrc[j+1], s2 = ssrc[j+2], s3 = ssrc[j+3];
        float4 v0 = g4[((size_t)s0 << 4) + q];
        float4 v1 = g4[((size_t)s1 << 4) + q];
        float4 v2 = g4[((size_t)s2 << 4) + q];
        float4 v3 = g4[((size_t)s3 << 4) + q];
        a.x += (v0.x + v1.x) + (v2.x + v3.x);
        a.y += (v0.y + v1.y) + (v2.y + v3.y);
        a.z += (v0.z + v1.z) + (v2.z + v3.z);
        a.w += (v0.w + v1.w) + (v2.w + v3.w);
    }
    for (; j < end; ++j) {
        float4 v = g4[((size_t)ssrc[j] << 4) + q];
        a.x += v.x; a.y += v.y; a.z += v.z; a.w += v.w;
    }
    float dv = dinv[node];
    float4 bb = bias4[q];
    a.x = fmaxf(fmaf(a.x, dv, bb.x), 0.f);
    a.y = fmaxf(fmaf(a.y, dv, bb.y), 0.f);
    a.z = fmaxf(fmaf(a.z, dv, bb.z), 0.f);
    a.w = fmaxf(fmaf(a.w, dv, bb.w), 0.f);
    out4[((size_t)node << 4) + q] = a;
}

// ---------------- dense linears (thread-per-node register GEMM) ------------

__global__ __launch_bounds__(TPB) void k_lin64n(const float* __restrict__ h,
                                                const float* __restrict__ W,
                                                const float* __restrict__ dinv,
                                                float* __restrict__ g, int N) {
    int node = blockIdx.x * TPB + threadIdx.x;
    if (node >= N) return;
    const float4* hp = (const float4*)(h + ((size_t)node << 6));
    float acc[64];
#pragma unroll
    for (int f = 0; f < 64; ++f) acc[f] = 0.f;
    for (int kb = 0; kb < 16; ++kb) {
        float4 hv = hp[kb];
        const float* Wr = W + (__builtin_amdgcn_readfirstlane(kb) << 8);
#pragma unroll
        for (int f = 0; f < 64; ++f) {
            float a = acc[f];
            a = fmaf(hv.x, Wr[f],        a);
            a = fmaf(hv.y, Wr[64  + f],  a);
            a = fmaf(hv.z, Wr[128 + f],  a);
            a = fmaf(hv.w, Wr[192 + f],  a);
            acc[f] = a;
        }
    }
    float dv = dinv[node];
    float4* gp = (float4*)(g + ((size_t)node << 6));
#pragma unroll
    for (int i = 0; i < 16; ++i) {
        float4 v;
        v.x = acc[4*i+0] * dv;
        v.y = acc[4*i+1] * dv;
        v.z = acc[4*i+2] * dv;
        v.w = acc[4*i+3] * dv;
        gp[i] = v;
    }
}

__global__ __launch_bounds__(TPB) void k_lin64_3n(const float* __restrict__ h,
                                                  const float* __restrict__ W,
                                                  const float* __restrict__ dinv,
                                                  float* __restrict__ g34, int N) {
    int node = blockIdx.x * TPB + threadIdx.x;
    if (node >= N) return;
    const float4* hp = (const float4*)(h + ((size_t)node << 6));
    float a0 = 0.f, a1 = 0.f, a2 = 0.f;
    for (int kb = 0; kb < 16; ++kb) {
        float4 hv = hp[kb];
        const float* Wr = W + __builtin_amdgcn_readfirstlane(kb) * 12;
        a0 = fmaf(hv.x, Wr[0],  a0); a1 = fmaf(hv.x, Wr[1],  a1); a2 = fmaf(hv.x, Wr[2],  a2);
        a0 = fmaf(hv.y, Wr[3],  a0); a1 = fmaf(hv.y, Wr[4],  a1); a2 = fmaf(hv.y, Wr[5],  a2);
        a0 = fmaf(hv.z, Wr[6],  a0); a1 = fmaf(hv.z, Wr[7],  a1); a2 = fmaf(hv.z, Wr[8],  a2);
        a0 = fmaf(hv.w, Wr[9],  a0); a1 = fmaf(hv.w, Wr[10], a1); a2 = fmaf(hv.w, Wr[11], a2);
    }
    float dv = dinv[node];
    float4 v;
    v.x = a0 * dv; v.y = a1 * dv; v.z = a2 * dv; v.w = 0.f;
    ((float4*)g34)[node] = v;
}

extern "C" void kernel_launch(void* const* d_in, const int* in_sizes, int n_in,
                              void* d_out, int out_size, void* d_ws, size_t ws_size,
                              hipStream_t stream) {
    const float* x  = (const float*)d_in[0];
    const int*   ei = (const int*)  d_in[1];
    const float* W1 = (const float*)d_in[2];
    const float* b1 = (const float*)d_in[3];
    const float* W2 = (const float*)d_in[4];
    const float* b2 = (const float*)d_in[5];
    const float* W3 = (const float*)d_in[6];
    const float* b3 = (const float*)d_in[7];
    float* out = (float*)d_out;

    const int N = in_sizes[0] / 3;       // 100000
    const int E = in_sizes[1] / 2;       // 1600000
    const int* srcI = ei;
    const int* dstI = ei + E;

    // workspace layout (4-byte units); bkt aliases g (bkt dead before g written)
    float*    ws      = (float*)d_ws;
    unsigned* gcount  = (unsigned*)ws;                      // @0      [512]
    int*      cptr    = (int*)     (ws + 512);              // @512    [512]
    unsigned* gcur    = (unsigned*)(ws + 1024);             // @1024   [512]
    int*      row_ptr = (int*)     (ws + 1536);             // [N+4]
    float*    dinv    = ws + 1536 + (N + 4);                // [N]
    int*      ssrc    = (int*)     (dinv + N);              // [E]
    float*    xs4     = (float*)(ssrc + E);                 // [4N]
    float*    q4      = xs4 + (size_t)N * 4;                // [4N]  (g34)
    float*    g       = q4  + (size_t)N * 4;                // [64N]
    float*    h       = g   + (size_t)N * 64;               // [64N]
    unsigned* bkt     = (unsigned*)g;                       // [E] alias

    hipMemsetAsync(gcount, 0, 512 * sizeof(unsigned), stream);

    int gPlace = (E + CH - 1) / CH;                         // 196
    int gS3    = (N * 4 + TPB - 1) / TPB;                   // 1563
    int gN     = (N + TPB - 1) / TPB;                       // 391
    int gP64   = (int)(((size_t)N * 16 + TPB - 1) / TPB);   // 6250

    // graph preprocessing: two-phase counting sort -> per-node CSR + dinv
    k_hist  <<<384,    TPB, 0, stream>>>(dstI, gcount, E);
    k_scan  <<<1,      512, 0, stream>>>(gcount, cptr, gcur, E);
    k_placeA<<<gPlace, TPB, 0, stream>>>(srcI, dstI, gcur, bkt, E);
    k_fine  <<<NB,     TPB, 0, stream>>>(bkt, cptr, row_ptr, ssrc, dinv, N, E);

    // layer 1: scale, fused pull+linear+relu
    k_scale3<<<gS3, TPB, 0, stream>>>(x, dinv, xs4, N);
    k_l1    <<<gS3, TPB, 0, stream>>>(xs4, row_ptr, ssrc, dinv, W1, b1, h, N);

    // layer 2: linear (register GEMM), 16-lane float4 pull (+bias+relu fused)
    k_lin64n <<<gN,   TPB, 0, stream>>>(h, W2, dinv, g, N);
    k_pull64q<<<gP64, TPB, 0, stream>>>((const float4*)g, row_ptr, ssrc, dinv,
                                        (const float4*)b2, (float4*)h, N);

    // layer 3: linear to 3 (padded 4), pull 3-wide (+bias fused)
    k_lin64_3n<<<gN,  TPB, 0, stream>>>(h, W3, dinv, q4, N);
    k_pull3o  <<<gS3, TPB, 0, stream>>>(q4, row_ptr, ssrc, dinv, b3, out, N);
}

// Round 7
// 260.715 us; speedup vs baseline: 4.0314x; 1.1173x over previous
//
#include <hip/hip_runtime.h>

#define TPB 256
#define NB 391            // ceil(100000/256) coarse buckets of 256 nodes
#define CH 8192           // edges per k_placeA block

// ---------------- coarse histogram (LDS-privatized) ----------------

__global__ __launch_bounds__(TPB) void k_hist(const int* __restrict__ dst,
                                              unsigned* __restrict__ gcount, int E) {
    __shared__ unsigned c[512];
    int t = threadIdx.x;
    for (int b = t; b < 512; b += TPB) c[b] = 0;
    __syncthreads();
    int stride = gridDim.x * TPB;
    for (int i = blockIdx.x * TPB + t; i < E; i += stride)
        atomicAdd(&c[(unsigned)dst[i] >> 8], 1u);
    __syncthreads();
    for (int b = t; b < NB; b += TPB)
        if (c[b]) atomicAdd(&gcount[b], c[b]);
}

// ---------------- exclusive scan over NB buckets (1 block) ----------------

__global__ __launch_bounds__(512) void k_scan(const unsigned* __restrict__ gcount,
                                              int* __restrict__ cptr,
                                              unsigned* __restrict__ gcur, int E) {
    __shared__ unsigned s[512];
    int t = threadIdx.x;
    unsigned orig = (t < NB) ? gcount[t] : 0u;
    s[t] = orig;
    __syncthreads();
#pragma unroll
    for (int o = 1; o < 512; o <<= 1) {
        unsigned v = (t >= o) ? s[t - o] : 0u;
        __syncthreads();
        s[t] += v;
        __syncthreads();
    }
    if (t < NB) {
        unsigned ex = s[t] - orig;
        cptr[t] = (int)ex;
        gcur[t] = ex;
    }
    if (t == 0) cptr[NB] = E;
}

// ---------------- chunked coarse bucket sort, LDS-staged grouped writes ----
// packs each edge as  src | ((dst & 255) << 20)

__global__ __launch_bounds__(TPB) void k_placeA(const int* __restrict__ src,
                                                const int* __restrict__ dst,
                                                unsigned* __restrict__ gcur,
                                                unsigned* __restrict__ bkt, int E) {
    __shared__ unsigned val[CH];
    __shared__ unsigned short bid[CH];
    __shared__ unsigned cnt[512], loff[512], lcur[512], basev[512];
    __shared__ unsigned tsum[TPB];
    int t = threadIdx.x;
    int c0 = blockIdx.x * CH;
    int n = E - c0; if (n > CH) n = CH;

    for (int b = t; b < 512; b += TPB) { cnt[b] = 0; lcur[b] = 0; }
    __syncthreads();
    for (int i = t; i < n; i += TPB)
        atomicAdd(&cnt[(unsigned)dst[c0 + i] >> 8], 1u);
    __syncthreads();
    for (int b = t; b < NB; b += TPB)
        basev[b] = cnt[b] ? atomicAdd(&gcur[b], cnt[b]) : 0u;
    unsigned a0 = cnt[2 * t], a1 = cnt[2 * t + 1];
    tsum[t] = a0 + a1;
    __syncthreads();
#pragma unroll
    for (int o = 1; o < TPB; o <<= 1) {
        unsigned v = (t >= o) ? tsum[t - o] : 0u;
        __syncthreads();
        tsum[t] += v;
        __syncthreads();
    }
    unsigned ex = tsum[t] - (a0 + a1);
    loff[2 * t] = ex; loff[2 * t + 1] = ex + a0;
    __syncthreads();
    for (int i = t; i < n; i += TPB) {
        unsigned s = (unsigned)src[c0 + i];
        unsigned d = (unsigned)dst[c0 + i];
        unsigned b = d >> 8;
        unsigned r = atomicAdd(&lcur[b], 1u);
        unsigned slot = loff[b] + r;
        val[slot] = s | ((d & 255u) << 20);
        bid[slot] = (unsigned short)b;
    }
    __syncthreads();
    for (int i = t; i < n; i += TPB) {
        unsigned b = bid[i];
        bkt[basev[b] + ((unsigned)i - loff[b])] = val[i];
    }
}

// ---------------- fine sort within bucket -> CSR + dinv + xs4 --------------

__global__ __launch_bounds__(TPB) void k_fineS(const unsigned* __restrict__ bkt,
                                               const int* __restrict__ cptr,
                                               const float* __restrict__ x,
                                               int* __restrict__ row_ptr,
                                               int* __restrict__ ssrc,
                                               float* __restrict__ dinv,
                                               float4* __restrict__ xs4,
                                               int N, int E) {
    __shared__ unsigned cnt[256], sc[256], off[256];
    int t = threadIdx.x, b = blockIdx.x;
    cnt[t] = 0;
    __syncthreads();
    int p0 = cptr[b], p1 = cptr[b + 1];
    for (int i = p0 + t; i < p1; i += TPB)
        atomicAdd(&cnt[bkt[i] >> 20], 1u);
    __syncthreads();
    unsigned c = cnt[t];
    sc[t] = c;
    __syncthreads();
#pragma unroll
    for (int o = 1; o < 256; o <<= 1) {
        unsigned v = (t >= o) ? sc[t - o] : 0u;
        __syncthreads();
        sc[t] += v;
        __syncthreads();
    }
    unsigned ex = sc[t] - c;
    off[t] = ex;
    int node = (b << 8) + t;
    if (node < N) {
        row_ptr[node] = p0 + (int)ex;
        float dv = rsqrtf((float)(c + 1u));   // +1 = self-loop
        dinv[node] = dv;
        float4 xv;
        xv.x = x[node * 3 + 0] * dv;
        xv.y = x[node * 3 + 1] * dv;
        xv.z = x[node * 3 + 2] * dv;
        xv.w = 0.f;
        xs4[node] = xv;
    }
    if (b == NB - 1 && t == 0) row_ptr[N] = E;
    __syncthreads();
    for (int i = p0 + t; i < p1; i += TPB) {
        unsigned u = bkt[i];
        unsigned r = atomicAdd(&off[u >> 20], 1u);
        ssrc[p0 + (int)r] = (int)(u & 0xFFFFFu);
    }
}

// ---------------- fused layer 1 + layer-2 linear (thread-per-node) ---------
// q = dinv*(self + sum nbr xs4);  h1 = relu(q W1 + b1) computed on the fly;
// g = dinv * (h1 W2).  W1/W2 read at wave-uniform addresses (scalar path).

__global__ __launch_bounds__(TPB) void k_l1f(const float4* __restrict__ xs4,
                                             const int* __restrict__ row_ptr,
                                             const int* __restrict__ ssrc,
                                             const float* __restrict__ dinv,
                                             const float* __restrict__ W1,
                                             const float* __restrict__ b1,
                                             const float* __restrict__ W2,
                                             float* __restrict__ g, int N) {
    int node = blockIdx.x * TPB + threadIdx.x;
    if (node >= N) return;
    int beg = row_ptr[node], end = row_ptr[node + 1];
    float4 q = xs4[node];                       // self-loop
    int j = beg;
    for (; j + 3 < end; j += 4) {
        int s0 = ssrc[j], s1 = ssrc[j+1], s2 = ssrc[j+2], s3 = ssrc[j+3];
        float4 v0 = xs4[s0], v1 = xs4[s1], v2 = xs4[s2], v3 = xs4[s3];
        q.x += (v0.x + v1.x) + (v2.x + v3.x);
        q.y += (v0.y + v1.y) + (v2.y + v3.y);
        q.z += (v0.z + v1.z) + (v2.z + v3.z);
    }
    for (; j < end; ++j) {
        float4 v = xs4[ssrc[j]];
        q.x += v.x; q.y += v.y; q.z += v.z;
    }
    float dv = dinv[node];
    float q0 = q.x * dv, q1 = q.y * dv, q2 = q.z * dv;

    float acc[64];
#pragma unroll
    for (int f = 0; f < 64; ++f) acc[f] = 0.f;
    for (int kb = 0; kb < 16; ++kb) {
        int k0 = __builtin_amdgcn_readfirstlane(kb) << 2;
        const float* W1k = W1 + k0;             // W1[c*64 + k0+i]
        const float* b1k = b1 + k0;
        float4 hv;
        hv.x = fmaxf(fmaf(q0, W1k[0], fmaf(q1, W1k[64], fmaf(q2, W1k[128], b1k[0]))), 0.f);
        hv.y = fmaxf(fmaf(q0, W1k[1], fmaf(q1, W1k[65], fmaf(q2, W1k[129], b1k[1]))), 0.f);
        hv.z = fmaxf(fmaf(q0, W1k[2], fmaf(q1, W1k[66], fmaf(q2, W1k[130], b1k[2]))), 0.f);
        hv.w = fmaxf(fmaf(q0, W1k[3], fmaf(q1, W1k[67], fmaf(q2, W1k[131], b1k[3]))), 0.f);
        const float* Wr = W2 + (k0 << 6);       // W2[(k0+i)*64 + f]
#pragma unroll
        for (int f = 0; f < 64; ++f) {
            float a = acc[f];
            a = fmaf(hv.x, Wr[f],        a);
            a = fmaf(hv.y, Wr[64  + f],  a);
            a = fmaf(hv.z, Wr[128 + f],  a);
            a = fmaf(hv.w, Wr[192 + f],  a);
            acc[f] = a;
        }
    }
    float4* gp = (float4*)(g + ((size_t)node << 6));
#pragma unroll
    for (int i = 0; i < 16; ++i) {
        float4 v;
        v.x = acc[4*i+0] * dv;
        v.y = acc[4*i+1] * dv;
        v.z = acc[4*i+2] * dv;
        v.w = acc[4*i+3] * dv;
        gp[i] = v;
    }
}

// ---------------- fused layer-2 pull + bias/relu + layer-3 linear ----------
// 16 lanes/node, float4 per lane. h2 stays in registers; lin3 partials
// reduced across the 16-lane group with shuffle-xor; g34 = dinv*(h2 W3).

__global__ __launch_bounds__(TPB) void k_p2f(const float4* __restrict__ g4,
                                             const int* __restrict__ row_ptr,
                                             const int* __restrict__ ssrc,
                                             const float* __restrict__ dinv,
                                             const float4* __restrict__ bias4,
                                             const float* __restrict__ W3,
                                             float4* __restrict__ g34, int N) {
    int tid = blockIdx.x * TPB + threadIdx.x;
    int node = tid >> 4, q = tid & 15;
    if (node >= N) return;
    int beg = row_ptr[node], end = row_ptr[node + 1];
    float4 a = g4[((size_t)node << 4) + q];     // self-loop
    int j = beg;
    for (; j + 3 < end; j += 4) {
        int s0 = ssrc[j], s1 = ssrc[j+1], s2 = ssrc[j+2], s3 = ssrc[j+3];
        float4 v0 = g4[((size_t)s0 << 4) + q];
        float4 v1 = g4[((size_t)s1 << 4) + q];
        float4 v2 = g4[((size_t)s2 << 4) + q];
        float4 v3 = g4[((size_t)s3 << 4) + q];
        a.x += (v0.x + v1.x) + (v2.x + v3.x);
        a.y += (v0.y + v1.y) + (v2.y + v3.y);
        a.z += (v0.z + v1.z) + (v2.z + v3.z);
        a.w += (v0.w + v1.w) + (v2.w + v3.w);
    }
    for (; j < end; ++j) {
        float4 v = g4[((size_t)ssrc[j] << 4) + q];
        a.x += v.x; a.y += v.y; a.z += v.z; a.w += v.w;
    }
    float dv = dinv[node];
    float4 bb = bias4[q];
    a.x = fmaxf(fmaf(a.x, dv, bb.x), 0.f);      // h2 features 4q..4q+3
    a.y = fmaxf(fmaf(a.y, dv, bb.y), 0.f);
    a.z = fmaxf(fmaf(a.z, dv, bb.z), 0.f);
    a.w = fmaxf(fmaf(a.w, dv, bb.w), 0.f);
    // lin3 partials: p_c = sum_{f in my 4} h_f * W3[f][c]
    const float* Wr = W3 + q * 12;              // W3[(4q+i)*3 + c] = Wr[3i+c]
    float p0 = fmaf(a.x, Wr[0], fmaf(a.y, Wr[3], fmaf(a.z, Wr[6], a.w * Wr[9])));
    float p1 = fmaf(a.x, Wr[1], fmaf(a.y, Wr[4], fmaf(a.z, Wr[7], a.w * Wr[10])));
    float p2 = fmaf(a.x, Wr[2], fmaf(a.y, Wr[5], fmaf(a.z, Wr[8], a.w * Wr[11])));
#pragma unroll
    for (int off = 1; off < 16; off <<= 1) {    // reduce within 16-lane group
        p0 += __shfl_xor(p0, off, 64);
        p1 += __shfl_xor(p1, off, 64);
        p2 += __shfl_xor(p2, off, 64);
    }
    if (q == 0) {
        float4 v;
        v.x = p0 * dv; v.y = p1 * dv; v.z = p2 * dv; v.w = 0.f;
        g34[node] = v;
    }
}

// ---------------- layer-3 pull with output epilogue ----------------

__global__ __launch_bounds__(TPB) void k_pull3o(const float* __restrict__ g34,
                                                const int* __restrict__ row_ptr,
                                                const int* __restrict__ ssrc,
                                                const float* __restrict__ dinv,
                                                const float* __restrict__ b3,
                                                float* __restrict__ out, int N) {
    int tid = blockIdx.x * TPB + threadIdx.x;
    int node = tid >> 2, c = tid & 3;
    if (node >= N) return;
    int beg = row_ptr[node], end = row_ptr[node + 1];
    float acc = g34[tid];                       // self-loop
    int j = beg;
    for (; j + 3 < end; j += 4) {
        int s0 = ssrc[j], s1 = ssrc[j+1], s2 = ssrc[j+2], s3 = ssrc[j+3];
        acc += (g34[(s0 << 2) + c] + g34[(s1 << 2) + c])
             + (g34[(s2 << 2) + c] + g34[(s3 << 2) + c]);
    }
    for (; j < end; ++j) acc += g34[(ssrc[j] << 2) + c];
    if (c < 3) out[(size_t)node * 3 + c] = dinv[node] * acc + b3[c];
}

extern "C" void kernel_launch(void* const* d_in, const int* in_sizes, int n_in,
                              void* d_out, int out_size, void* d_ws, size_t ws_size,
                              hipStream_t stream) {
    const float* x  = (const float*)d_in[0];
    const int*   ei = (const int*)  d_in[1];
    const float* W1 = (const float*)d_in[2];
    const float* b1 = (const float*)d_in[3];
    const float* W2 = (const float*)d_in[4];
    const float* b2 = (const float*)d_in[5];
    const float* W3 = (const float*)d_in[6];
    const float* b3 = (const float*)d_in[7];
    float* out = (float*)d_out;

    const int N = in_sizes[0] / 3;       // 100000
    const int E = in_sizes[1] / 2;       // 1600000
    const int* srcI = ei;
    const int* dstI = ei + E;

    // workspace layout (4-byte units); bkt aliases g (bkt dead before g written)
    float*    ws      = (float*)d_ws;
    unsigned* gcount  = (unsigned*)ws;                      // @0      [512]
    int*      cptr    = (int*)     (ws + 512);              // @512    [512]
    unsigned* gcur    = (unsigned*)(ws + 1024);             // @1024   [512]
    int*      row_ptr = (int*)     (ws + 1536);             // [N+4]
    float*    dinv    = ws + 1536 + (N + 4);                // [N]
    int*      ssrc    = (int*)     (dinv + N);              // [E]
    float*    xs4     = (float*)(ssrc + E);                 // [4N]
    float*    q4      = xs4 + (size_t)N * 4;                // [4N]  (g34)
    float*    g       = q4  + (size_t)N * 4;                // [64N]
    unsigned* bkt     = (unsigned*)g;                       // [E] alias

    hipMemsetAsync(gcount, 0, 512 * sizeof(unsigned), stream);

    int gPlace = (E + CH - 1) / CH;                         // 196
    int gS3    = (N * 4 + TPB - 1) / TPB;                   // 1563
    int gN     = (N + TPB - 1) / TPB;                       // 391
    int gP64   = (int)(((size_t)N * 16 + TPB - 1) / TPB);   // 6250

    // graph preprocessing: two-phase counting sort -> CSR + dinv + xs4
    k_hist  <<<384,    TPB, 0, stream>>>(dstI, gcount, E);
    k_scan  <<<1,      512, 0, stream>>>(gcount, cptr, gcur, E);
    k_placeA<<<gPlace, TPB, 0, stream>>>(srcI, dstI, gcur, bkt, E);
    k_fineS <<<NB,     TPB, 0, stream>>>(bkt, cptr, x, row_ptr, ssrc, dinv,
                                         (float4*)xs4, N, E);

    // layer 1 + layer-2 linear fused (h1 never materialized)
    k_l1f<<<gN, TPB, 0, stream>>>((const float4*)xs4, row_ptr, ssrc, dinv,
                                  W1, b1, W2, g, N);

    // layer-2 pull + bias/relu + layer-3 linear fused (h2 never materialized)
    k_p2f<<<gP64, TPB, 0, stream>>>((const float4*)g, row_ptr, ssrc, dinv,
                                    (const float4*)b2, W3, (float4*)q4, N);

    // layer-3 pull (+bias fused)
    k_pull3o<<<gS3, TPB, 0, stream>>>(q4, row_ptr, ssrc, dinv, b3, out, N);
}